// Round 1
// baseline (704.030 us; speedup 1.0000x reference)
//
#include <hip/hip_runtime.h>
#include <stdint.h>

#define T_TOK 32768
#define DDIM 512
#define HID 1024
#define NEXP 8

typedef _Float16 f16;
typedef _Float16 f16x8 __attribute__((ext_vector_type(8)));
typedef _Float16 f16x4 __attribute__((ext_vector_type(4)));
typedef float f32x4 __attribute__((ext_vector_type(4)));

__device__ __forceinline__ void gload_lds16(const void* g, void* l) {
  __builtin_amdgcn_global_load_lds(
      (__attribute__((address_space(1))) void*)g,
      (__attribute__((address_space(3))) void*)l, 16, 0, 0);
}

// ---------------- x fp32 -> fp16 ----------------
__global__ void k_cvt_x(const float* __restrict__ x, f16* __restrict__ xh) {
  int i = blockIdx.x * blockDim.x + threadIdx.x;  // over T*D/4
  float4 v = ((const float4*)x)[i];
  f16x4 o = {(f16)v.x, (f16)v.y, (f16)v.z, (f16)v.w};
  ((f16x4*)xh)[i] = o;
}

// ---------------- W [K][N] fp32 -> Wt [N][K] fp16 (per expert) ----------------
__global__ void k_transpose(const float* __restrict__ W, f16* __restrict__ Wt,
                            const int K, const int N) {
  __shared__ float tile[64][65];
  const int e = blockIdx.z;
  const float* Wb = W + (size_t)e * K * N;
  f16* Wtb = Wt + (size_t)e * K * N;
  const int k0 = blockIdx.x * 64, n0 = blockIdx.y * 64;
  const int tr = threadIdx.x >> 2;          // 0..63
  const int tc = (threadIdx.x & 3) * 16;    // 0,16,32,48
#pragma unroll
  for (int j = 0; j < 16; j += 4) {
    float4 v = *(const float4*)&Wb[(size_t)(k0 + tr) * N + n0 + tc + j];
    tile[tr][tc + j + 0] = v.x; tile[tr][tc + j + 1] = v.y;
    tile[tr][tc + j + 2] = v.z; tile[tr][tc + j + 3] = v.w;
  }
  __syncthreads();
  f16x8 t0, t1;
#pragma unroll
  for (int j = 0; j < 8; ++j) {
    t0[j] = (f16)tile[tc + j][tr];
    t1[j] = (f16)tile[tc + 8 + j][tr];
  }
  *(f16x8*)&Wtb[(size_t)(n0 + tr) * K + k0 + tc] = t0;
  *(f16x8*)&Wtb[(size_t)(n0 + tr) * K + k0 + tc + 8] = t1;
}

// ---------------- gating: wave per token ----------------
__global__ void k_gate(const float* __restrict__ x, const float* __restrict__ gw,
                       int* __restrict__ route_e, float* __restrict__ route_w,
                       int* __restrict__ cnt) {
  __shared__ int scnt[NEXP];
  const int tid = threadIdx.x, lane = tid & 63, wv = tid >> 6;
  if (tid < NEXP) scnt[tid] = 0;
  __syncthreads();

  float ga[4][8], gb[4][8];
#pragma unroll
  for (int j = 0; j < 4; ++j) {
    const int r0 = lane * 4 + j;
    const int r1 = 256 + lane * 4 + j;
    float4 q0 = *(const float4*)&gw[r0 * 8];
    float4 q1 = *(const float4*)&gw[r0 * 8 + 4];
    ga[j][0] = q0.x; ga[j][1] = q0.y; ga[j][2] = q0.z; ga[j][3] = q0.w;
    ga[j][4] = q1.x; ga[j][5] = q1.y; ga[j][6] = q1.z; ga[j][7] = q1.w;
    q0 = *(const float4*)&gw[r1 * 8];
    q1 = *(const float4*)&gw[r1 * 8 + 4];
    gb[j][0] = q0.x; gb[j][1] = q0.y; gb[j][2] = q0.z; gb[j][3] = q0.w;
    gb[j][4] = q1.x; gb[j][5] = q1.y; gb[j][6] = q1.z; gb[j][7] = q1.w;
  }

  const int tbase = blockIdx.x * 32 + wv * 8;
  for (int it = 0; it < 8; ++it) {
    const int t = tbase + it;
    const float4 A = *(const float4*)&x[(size_t)t * DDIM + lane * 4];
    const float4 B = *(const float4*)&x[(size_t)t * DDIM + 256 + lane * 4];
    float p[8];
#pragma unroll
    for (int e = 0; e < 8; ++e) {
      p[e] = A.x * ga[0][e] + A.y * ga[1][e] + A.z * ga[2][e] + A.w * ga[3][e] +
             B.x * gb[0][e] + B.y * gb[1][e] + B.z * gb[2][e] + B.w * gb[3][e];
    }
#pragma unroll
    for (int off = 32; off >= 1; off >>= 1) {
#pragma unroll
      for (int e = 0; e < 8; ++e) p[e] += __shfl_xor(p[e], off);
    }
    if (lane == 0) {
      int e1 = 0;
#pragma unroll
      for (int e = 1; e < 8; ++e) if (p[e] > p[e1]) e1 = e;   // lowest idx on tie
      int e2 = (e1 == 0) ? 1 : 0;
#pragma unroll
      for (int e = 0; e < 8; ++e) if (e != e1 && p[e] > p[e2]) e2 = e;
      const float wa = 1.0f / (1.0f + expf(p[e2] - p[e1]));   // normalized top-2 softmax
      route_e[t] = e1 | (e2 << 8);
      route_w[t] = wa;
      atomicAdd(&scnt[e1], 1);
      atomicAdd(&scnt[e2], 1);
    }
  }
  __syncthreads();
  if (tid < NEXP) atomicAdd(&cnt[tid], scnt[tid]);
}

// ---------------- scan + balance loss ----------------
__global__ void k_scan(const int* __restrict__ cnt, int* __restrict__ base,
                       int* __restrict__ cursor, float* __restrict__ out_loss) {
  if (threadIdx.x == 0) {
    int b = 0;
    float loss = 0.0f;
    for (int e = 0; e < NEXP; ++e) {
      base[e] = b;
      cursor[e] = b;
      b += cnt[e];
      float u = (float)cnt[e] / (float)T_TOK - 0.125f;
      loss += u * u;
    }
    *out_loss = loss * 0.01f;   // mean*E*W = sum/8*8*0.01
  }
}

// ---------------- scatter into per-expert compact lists ----------------
__global__ void k_scatter(const int* __restrict__ route_e, const float* __restrict__ route_w,
                          int* __restrict__ cursor, int* __restrict__ tok_slot,
                          float* __restrict__ wgt_slot) {
  const int t = blockIdx.x * blockDim.x + threadIdx.x;
  const int lane = threadIdx.x & 63;
  const int re = route_e[t];
  const float wa = route_w[t];
  const int e1 = re & 0xff, e2 = re >> 8;
#pragma unroll
  for (int e = 0; e < NEXP; ++e) {
    unsigned long long m = __ballot(e1 == e);
    if (m) {
      const int leader = __ffsll(m) - 1;
      int b0 = 0;
      if (lane == leader) b0 = atomicAdd(&cursor[e], __popcll(m));
      b0 = __shfl(b0, leader);
      if (e1 == e) {
        const int pos = b0 + __popcll(m & ((1ull << lane) - 1));
        tok_slot[pos] = t;
        wgt_slot[pos] = wa;
      }
    }
    m = __ballot(e2 == e);
    if (m) {
      const int leader = __ffsll(m) - 1;
      int b0 = 0;
      if (lane == leader) b0 = atomicAdd(&cursor[e], __popcll(m));
      b0 = __shfl(b0, leader);
      if (e2 == e) {
        const int pos = b0 + __popcll(m & ((1ull << lane) - 1));
        tok_slot[pos] = t;
        wgt_slot[pos] = 1.0f - wa;
      }
    }
  }
}

// ---------------- GEMM1: h = gelu(X_e @ w1[e] + b1[e]) ----------------
// 128x128 tile, BK=64, 4 waves (each 64x64), XOR-swizzled LDS, global_load_lds x16B.
__global__ __launch_bounds__(256) void k_mlp1(
    const f16* __restrict__ xh, const f16* __restrict__ w1t,
    const float* __restrict__ b1, f16* __restrict__ h,
    const int* __restrict__ tok_slot, const int* __restrict__ base,
    const int* __restrict__ cnt, const int hc, const int c0) {
  const int e = blockIdx.z;
  const int ne = cnt[e];
  const int m0 = blockIdx.x * 128;
  if (m0 >= ne) return;
  const int n0 = blockIdx.y * 128;
  const int sbase = base[e];
  const int slot0 = sbase + m0;
  const int shi = sbase + ne;

  __shared__ f16 As[128 * 64];
  __shared__ f16 Bs[128 * 64];

  const int tid = threadIdx.x;
  const int lane = tid & 63;
  const int wv = tid >> 6;
  const int wm = wv >> 1, wn = wv & 1;
  const int g = lane >> 4;
  const int l15 = lane & 15;

  const f16* aSrc[4];
  const f16* bSrc[4];
#pragma unroll
  for (int i = 0; i < 4; ++i) {
    const int ch = wv * 4 + i;
    const int row = ch * 8 + (lane >> 3);
    const int p = lane & 7;
    const int sw = (p ^ (row & 7)) * 8;
    int slot = slot0 + row;
    slot = (slot <= shi - 1) ? slot : (shi - 1);   // clamp padded rows
    const int tok = tok_slot[slot];
    aSrc[i] = xh + (size_t)tok * DDIM + sw;
    bSrc[i] = w1t + (size_t)(e * HID + c0 + n0 + row) * DDIM + sw;
  }

  f32x4 acc[4][4];
#pragma unroll
  for (int a = 0; a < 4; ++a)
#pragma unroll
    for (int b = 0; b < 4; ++b) { f32x4 z = {0.f, 0.f, 0.f, 0.f}; acc[a][b] = z; }

  for (int ks = 0; ks < DDIM / 64; ++ks) {
    const int k0 = ks * 64;
#pragma unroll
    for (int i = 0; i < 4; ++i) {
      gload_lds16(aSrc[i] + k0, &As[(wv * 4 + i) * 512]);
      gload_lds16(bSrc[i] + k0, &Bs[(wv * 4 + i) * 512]);
    }
    __syncthreads();
#pragma unroll
    for (int kb = 0; kb < 2; ++kb) {
      f16x8 af[4], bf[4];
#pragma unroll
      for (int mf = 0; mf < 4; ++mf) {
        const int row = wm * 64 + mf * 16 + l15;
        af[mf] = *(const f16x8*)&As[row * 64 + (((kb * 4 + g) ^ (row & 7)) * 8)];
      }
#pragma unroll
      for (int nf = 0; nf < 4; ++nf) {
        const int row = wn * 64 + nf * 16 + l15;
        bf[nf] = *(const f16x8*)&Bs[row * 64 + (((kb * 4 + g) ^ (row & 7)) * 8)];
      }
#pragma unroll
      for (int mf = 0; mf < 4; ++mf)
#pragma unroll
        for (int nf = 0; nf < 4; ++nf)
          acc[mf][nf] = __builtin_amdgcn_mfma_f32_16x16x32_f16(af[mf], bf[nf], acc[mf][nf], 0, 0, 0);
    }
    __syncthreads();
  }

#pragma unroll
  for (int mf = 0; mf < 4; ++mf) {
#pragma unroll
    for (int r = 0; r < 4; ++r) {
      const int row = wm * 64 + mf * 16 + g * 4 + r;
      const int slot = slot0 + row;
      if (slot >= shi) continue;
#pragma unroll
      for (int nf = 0; nf < 4; ++nf) {
        const int col = wn * 64 + nf * 16 + l15;
        float v = acc[mf][nf][r] + b1[e * HID + c0 + n0 + col];
        v = 0.5f * v * (1.0f + erff(v * 0.70710678118654752f));  // exact gelu
        h[(size_t)slot * hc + n0 + col] = (f16)v;
      }
    }
  }
}

// ---------------- GEMM2: out += wgt * (h @ w2[e] + b2[e]) ----------------
__global__ __launch_bounds__(256) void k_mlp2(
    const f16* __restrict__ h, const f16* __restrict__ w2t,
    const float* __restrict__ b2, float* __restrict__ out,
    const int* __restrict__ tok_slot, const float* __restrict__ wgt_slot,
    const int* __restrict__ base, const int* __restrict__ cnt,
    const int hc, const int c0) {
  const int e = blockIdx.z;
  const int ne = cnt[e];
  const int m0 = blockIdx.x * 128;
  if (m0 >= ne) return;
  const int n0 = blockIdx.y * 128;
  const int sbase = base[e];
  const int slot0 = sbase + m0;
  const int shi = sbase + ne;

  __shared__ f16 As[128 * 64];
  __shared__ f16 Bs[128 * 64];

  const int tid = threadIdx.x;
  const int lane = tid & 63;
  const int wv = tid >> 6;
  const int wm = wv >> 1, wn = wv & 1;
  const int g = lane >> 4;
  const int l15 = lane & 15;

  const f16* aSrc[4];
  const f16* bSrc[4];
#pragma unroll
  for (int i = 0; i < 4; ++i) {
    const int ch = wv * 4 + i;
    const int row = ch * 8 + (lane >> 3);
    const int p = lane & 7;
    const int sw = (p ^ (row & 7)) * 8;
    int slot = slot0 + row;
    slot = (slot <= 2 * T_TOK - 1) ? slot : (2 * T_TOK - 1);  // stay in h buffer
    aSrc[i] = h + (size_t)slot * hc + sw;
    bSrc[i] = w2t + (size_t)(e * DDIM + n0 + row) * HID + c0 + sw;
  }

  f32x4 acc[4][4];
#pragma unroll
  for (int a = 0; a < 4; ++a)
#pragma unroll
    for (int b = 0; b < 4; ++b) { f32x4 z = {0.f, 0.f, 0.f, 0.f}; acc[a][b] = z; }

  for (int ks = 0; ks < hc / 64; ++ks) {
    const int k0 = ks * 64;
#pragma unroll
    for (int i = 0; i < 4; ++i) {
      gload_lds16(aSrc[i] + k0, &As[(wv * 4 + i) * 512]);
      gload_lds16(bSrc[i] + k0, &Bs[(wv * 4 + i) * 512]);
    }
    __syncthreads();
#pragma unroll
    for (int kb = 0; kb < 2; ++kb) {
      f16x8 af[4], bf[4];
#pragma unroll
      for (int mf = 0; mf < 4; ++mf) {
        const int row = wm * 64 + mf * 16 + l15;
        af[mf] = *(const f16x8*)&As[row * 64 + (((kb * 4 + g) ^ (row & 7)) * 8)];
      }
#pragma unroll
      for (int nf = 0; nf < 4; ++nf) {
        const int row = wn * 64 + nf * 16 + l15;
        bf[nf] = *(const f16x8*)&Bs[row * 64 + (((kb * 4 + g) ^ (row & 7)) * 8)];
      }
#pragma unroll
      for (int mf = 0; mf < 4; ++mf)
#pragma unroll
        for (int nf = 0; nf < 4; ++nf)
          acc[mf][nf] = __builtin_amdgcn_mfma_f32_16x16x32_f16(af[mf], bf[nf], acc[mf][nf], 0, 0, 0);
    }
    __syncthreads();
  }

#pragma unroll
  for (int mf = 0; mf < 4; ++mf) {
#pragma unroll
    for (int r = 0; r < 4; ++r) {
      const int row = wm * 64 + mf * 16 + g * 4 + r;
      const int slot = slot0 + row;
      if (slot >= shi) continue;
      const int tok = tok_slot[slot];
      const float w = wgt_slot[slot];
      float* orow = out + (size_t)tok * DDIM + n0;
#pragma unroll
      for (int nf = 0; nf < 4; ++nf) {
        const int col = wn * 64 + nf * 16 + l15;
        float v = acc[mf][nf][r];
        if (c0 == 0) v += b2[e * DDIM + n0 + col];
        unsafeAtomicAdd(orow + col, w * v);
      }
    }
  }
}

extern "C" void kernel_launch(void* const* d_in, const int* in_sizes, int n_in,
                              void* d_out, int out_size, void* d_ws, size_t ws_size,
                              hipStream_t stream) {
  (void)in_sizes; (void)n_in;
  const float* x  = (const float*)d_in[0];
  const float* gw = (const float*)d_in[1];
  const float* w1 = (const float*)d_in[2];
  const float* b1 = (const float*)d_in[3];
  const float* w2 = (const float*)d_in[4];
  const float* b2 = (const float*)d_in[5];
  float* out = (float*)d_out;

  char* ws = (char*)d_ws;
  size_t off = 0;
  auto alloc = [&](size_t bytes) {
    char* p = ws + off;
    off += (bytes + 255) & ~(size_t)255;
    return p;
  };
  f16*   xh       = (f16*)  alloc((size_t)T_TOK * DDIM * 2);
  f16*   w1t      = (f16*)  alloc((size_t)NEXP * DDIM * HID * 2);
  f16*   w2t      = (f16*)  alloc((size_t)NEXP * DDIM * HID * 2);
  int*   route_e  = (int*)  alloc((size_t)T_TOK * 4);
  float* route_w  = (float*)alloc((size_t)T_TOK * 4);
  int*   tok_slot = (int*)  alloc((size_t)2 * T_TOK * 4);
  float* wgt_slot = (float*)alloc((size_t)2 * T_TOK * 4);
  int*   cnt      = (int*)  alloc(256);
  int*   base     = cnt + 8;
  int*   cursor   = cnt + 16;
  f16*   hbuf     = (f16*)(ws + off);
  const size_t havail = (ws_size > off) ? (ws_size - off) : 0;

  // smallest hidden-split whose h buffer fits the workspace
  int ns = 8;
  const int cands[4] = {1, 2, 4, 8};
  for (int i = 0; i < 4; ++i) {
    if ((size_t)2 * T_TOK * (HID / cands[i]) * 2 <= havail) { ns = cands[i]; break; }
  }
  const int hc = HID / ns;

  hipMemsetAsync(cnt, 0, 32, stream);
  hipMemsetAsync(d_out, 0, (size_t)out_size * sizeof(float), stream);

  k_cvt_x<<<dim3(T_TOK * DDIM / 4 / 256), 256, 0, stream>>>(x, xh);
  k_transpose<<<dim3(DDIM / 64, HID / 64, NEXP), 256, 0, stream>>>(w1, w1t, DDIM, HID);
  k_transpose<<<dim3(HID / 64, DDIM / 64, NEXP), 256, 0, stream>>>(w2, w2t, HID, DDIM);
  k_gate<<<dim3(T_TOK / 32), 256, 0, stream>>>(x, gw, route_e, route_w, cnt);
  k_scan<<<1, 64, 0, stream>>>(cnt, base, cursor, out + (size_t)T_TOK * DDIM);
  k_scatter<<<dim3(T_TOK / 256), 256, 0, stream>>>(route_e, route_w, cursor, tok_slot, wgt_slot);

  for (int c = 0; c < ns; ++c) {
    k_mlp1<<<dim3(256, hc / 128, NEXP), 256, 0, stream>>>(
        xh, w1t, b1, hbuf, tok_slot, base, cnt, hc, c * hc);
    k_mlp2<<<dim3(256, DDIM / 128, NEXP), 256, 0, stream>>>(
        hbuf, w2t, b2, out, tok_slot, wgt_slot, base, cnt, hc, c * hc);
  }
}

// Round 2
// 655.855 us; speedup vs baseline: 1.0735x; 1.0735x over previous
//
#include <hip/hip_runtime.h>
#include <stdint.h>

#define T_TOK 32768
#define DDIM 512
#define HID 1024
#define NEXP 8

typedef _Float16 f16;
typedef _Float16 f16x8 __attribute__((ext_vector_type(8)));
typedef _Float16 f16x4 __attribute__((ext_vector_type(4)));
typedef float f32x4 __attribute__((ext_vector_type(4)));

__device__ __forceinline__ void gload_lds16(const void* g, void* l) {
  __builtin_amdgcn_global_load_lds(
      (__attribute__((address_space(1))) void*)g,
      (__attribute__((address_space(3))) void*)l, 16, 0, 0);
}

// ---------------- x fp32 -> fp16 ----------------
__global__ void k_cvt_x(const float* __restrict__ x, f16* __restrict__ xh) {
  int i = blockIdx.x * blockDim.x + threadIdx.x;  // over T*D/4
  float4 v = ((const float4*)x)[i];
  f16x4 o = {(f16)v.x, (f16)v.y, (f16)v.z, (f16)v.w};
  ((f16x4*)xh)[i] = o;
}

// ---------------- W [K][N] fp32 -> Wt [N][K] fp16 (per expert) ----------------
__global__ void k_transpose(const float* __restrict__ W, f16* __restrict__ Wt,
                            const int K, const int N) {
  __shared__ float tile[64][65];
  const int e = blockIdx.z;
  const float* Wb = W + (size_t)e * K * N;
  f16* Wtb = Wt + (size_t)e * K * N;
  const int k0 = blockIdx.x * 64, n0 = blockIdx.y * 64;
  const int tr = threadIdx.x >> 2;          // 0..63
  const int tc = (threadIdx.x & 3) * 16;    // 0,16,32,48
#pragma unroll
  for (int j = 0; j < 16; j += 4) {
    float4 v = *(const float4*)&Wb[(size_t)(k0 + tr) * N + n0 + tc + j];
    tile[tr][tc + j + 0] = v.x; tile[tr][tc + j + 1] = v.y;
    tile[tr][tc + j + 2] = v.z; tile[tr][tc + j + 3] = v.w;
  }
  __syncthreads();
  f16x8 t0, t1;
#pragma unroll
  for (int j = 0; j < 8; ++j) {
    t0[j] = (f16)tile[tc + j][tr];
    t1[j] = (f16)tile[tc + 8 + j][tr];
  }
  *(f16x8*)&Wtb[(size_t)(n0 + tr) * K + k0 + tc] = t0;
  *(f16x8*)&Wtb[(size_t)(n0 + tr) * K + k0 + tc + 8] = t1;
}

// ---------------- gating: wave per token ----------------
__global__ void k_gate(const float* __restrict__ x, const float* __restrict__ gw,
                       int* __restrict__ route_e, float* __restrict__ route_w,
                       int* __restrict__ cnt) {
  __shared__ int scnt[NEXP];
  const int tid = threadIdx.x, lane = tid & 63, wv = tid >> 6;
  if (tid < NEXP) scnt[tid] = 0;
  __syncthreads();

  float ga[4][8], gb[4][8];
#pragma unroll
  for (int j = 0; j < 4; ++j) {
    const int r0 = lane * 4 + j;
    const int r1 = 256 + lane * 4 + j;
    float4 q0 = *(const float4*)&gw[r0 * 8];
    float4 q1 = *(const float4*)&gw[r0 * 8 + 4];
    ga[j][0] = q0.x; ga[j][1] = q0.y; ga[j][2] = q0.z; ga[j][3] = q0.w;
    ga[j][4] = q1.x; ga[j][5] = q1.y; ga[j][6] = q1.z; ga[j][7] = q1.w;
    q0 = *(const float4*)&gw[r1 * 8];
    q1 = *(const float4*)&gw[r1 * 8 + 4];
    gb[j][0] = q0.x; gb[j][1] = q0.y; gb[j][2] = q0.z; gb[j][3] = q0.w;
    gb[j][4] = q1.x; gb[j][5] = q1.y; gb[j][6] = q1.z; gb[j][7] = q1.w;
  }

  const int tbase = blockIdx.x * 32 + wv * 8;
  for (int it = 0; it < 8; ++it) {
    const int t = tbase + it;
    const float4 A = *(const float4*)&x[(size_t)t * DDIM + lane * 4];
    const float4 B = *(const float4*)&x[(size_t)t * DDIM + 256 + lane * 4];
    float p[8];
#pragma unroll
    for (int e = 0; e < 8; ++e) {
      p[e] = A.x * ga[0][e] + A.y * ga[1][e] + A.z * ga[2][e] + A.w * ga[3][e] +
             B.x * gb[0][e] + B.y * gb[1][e] + B.z * gb[2][e] + B.w * gb[3][e];
    }
#pragma unroll
    for (int off = 32; off >= 1; off >>= 1) {
#pragma unroll
      for (int e = 0; e < 8; ++e) p[e] += __shfl_xor(p[e], off);
    }
    if (lane == 0) {
      int e1 = 0;
#pragma unroll
      for (int e = 1; e < 8; ++e) if (p[e] > p[e1]) e1 = e;   // lowest idx on tie
      int e2 = (e1 == 0) ? 1 : 0;
#pragma unroll
      for (int e = 0; e < 8; ++e) if (e != e1 && p[e] > p[e2]) e2 = e;
      const float wa = 1.0f / (1.0f + expf(p[e2] - p[e1]));   // normalized top-2 softmax
      route_e[t] = e1 | (e2 << 8);
      route_w[t] = wa;
      atomicAdd(&scnt[e1], 1);
      atomicAdd(&scnt[e2], 1);
    }
  }
  __syncthreads();
  if (tid < NEXP) atomicAdd(&cnt[tid], scnt[tid]);
}

// ---------------- scan + balance loss ----------------
__global__ void k_scan(const int* __restrict__ cnt, int* __restrict__ base,
                       int* __restrict__ cursor, float* __restrict__ out_loss) {
  if (threadIdx.x == 0) {
    int b = 0;
    float loss = 0.0f;
    for (int e = 0; e < NEXP; ++e) {
      base[e] = b;
      cursor[e] = b;
      b += cnt[e];
      float u = (float)cnt[e] / (float)T_TOK - 0.125f;
      loss += u * u;
    }
    *out_loss = loss * 0.01f;   // mean*E*W = sum/8*8*0.01
  }
}

// ---------------- scatter into per-expert compact lists ----------------
__global__ void k_scatter(const int* __restrict__ route_e, const float* __restrict__ route_w,
                          int* __restrict__ cursor, int* __restrict__ tok_slot,
                          float* __restrict__ wgt_slot) {
  const int t = blockIdx.x * blockDim.x + threadIdx.x;
  const int lane = threadIdx.x & 63;
  const int re = route_e[t];
  const float wa = route_w[t];
  const int e1 = re & 0xff, e2 = re >> 8;
#pragma unroll
  for (int e = 0; e < NEXP; ++e) {
    unsigned long long m = __ballot(e1 == e);
    if (m) {
      const int leader = __ffsll(m) - 1;
      int b0 = 0;
      if (lane == leader) b0 = atomicAdd(&cursor[e], __popcll(m));
      b0 = __shfl(b0, leader);
      if (e1 == e) {
        const int pos = b0 + __popcll(m & ((1ull << lane) - 1));
        tok_slot[pos] = t;
        wgt_slot[pos] = wa;
      }
    }
    m = __ballot(e2 == e);
    if (m) {
      const int leader = __ffsll(m) - 1;
      int b0 = 0;
      if (lane == leader) b0 = atomicAdd(&cursor[e], __popcll(m));
      b0 = __shfl(b0, leader);
      if (e2 == e) {
        const int pos = b0 + __popcll(m & ((1ull << lane) - 1));
        tok_slot[pos] = t;
        wgt_slot[pos] = 1.0f - wa;
      }
    }
  }
}

// Stage one 128x64 A-tile + 128x64 B-tile K-chunk into given LDS buffers.
#define STAGE_TILE(k0_, As_, Bs_)                                   \
  do {                                                              \
    _Pragma("unroll") for (int i = 0; i < 4; ++i) {                 \
      gload_lds16(aSrc[i] + (k0_), &(As_)[(wv * 4 + i) * 512]);     \
      gload_lds16(bSrc[i] + (k0_), &(Bs_)[(wv * 4 + i) * 512]);     \
    }                                                               \
  } while (0)

// 64x64-per-wave MFMA compute on one staged K=64 chunk.
#define COMPUTE_TILE(As_, Bs_)                                                    \
  do {                                                                            \
    _Pragma("unroll") for (int kb = 0; kb < 2; ++kb) {                            \
      f16x8 af[4], bf[4];                                                         \
      _Pragma("unroll") for (int mf = 0; mf < 4; ++mf) {                          \
        const int row = wm * 64 + mf * 16 + l15;                                  \
        af[mf] = *(const f16x8*)&(As_)[row * 64 + (((kb * 4 + g) ^ (row & 7)) * 8)]; \
      }                                                                           \
      _Pragma("unroll") for (int nf = 0; nf < 4; ++nf) {                          \
        const int row = wn * 64 + nf * 16 + l15;                                  \
        bf[nf] = *(const f16x8*)&(Bs_)[row * 64 + (((kb * 4 + g) ^ (row & 7)) * 8)]; \
      }                                                                           \
      _Pragma("unroll") for (int mf = 0; mf < 4; ++mf)                            \
        _Pragma("unroll") for (int nf = 0; nf < 4; ++nf)                          \
          acc[mf][nf] =                                                           \
              __builtin_amdgcn_mfma_f32_16x16x32_f16(af[mf], bf[nf], acc[mf][nf], 0, 0, 0); \
    }                                                                             \
  } while (0)

// ---------------- GEMM1: h = gelu(X_e @ w1[e] + b1[e]) ----------------
// 128x128 tile, BK=64, 4 waves, XOR-swizzled LDS, 2-phase double-buffered pipeline.
__global__ __launch_bounds__(256) void k_mlp1(
    const f16* __restrict__ xh, const f16* __restrict__ w1t,
    const float* __restrict__ b1, f16* __restrict__ h,
    const int* __restrict__ tok_slot, const int* __restrict__ base,
    const int* __restrict__ cnt, const int hc, const int c0) {
  const int e = blockIdx.z;
  const int ne = cnt[e];
  const int m0 = blockIdx.x * 128;
  if (m0 >= ne) return;
  const int n0 = blockIdx.y * 128;
  const int sbase = base[e];
  const int slot0 = sbase + m0;
  const int shi = sbase + ne;

  __shared__ f16 As0[128 * 64];
  __shared__ f16 Bs0[128 * 64];
  __shared__ f16 As1[128 * 64];
  __shared__ f16 Bs1[128 * 64];

  const int tid = threadIdx.x;
  const int lane = tid & 63;
  const int wv = tid >> 6;
  const int wm = wv >> 1, wn = wv & 1;
  const int g = lane >> 4;
  const int l15 = lane & 15;

  const f16* aSrc[4];
  const f16* bSrc[4];
#pragma unroll
  for (int i = 0; i < 4; ++i) {
    const int ch = wv * 4 + i;
    const int row = ch * 8 + (lane >> 3);
    const int p = lane & 7;
    const int sw = (p ^ (row & 7)) * 8;
    int slot = slot0 + row;
    slot = (slot <= shi - 1) ? slot : (shi - 1);   // clamp padded rows
    const int tok = tok_slot[slot];
    aSrc[i] = xh + (size_t)tok * DDIM + sw;
    bSrc[i] = w1t + (size_t)(e * HID + c0 + n0 + row) * DDIM + sw;
  }

  f32x4 acc[4][4];
#pragma unroll
  for (int a = 0; a < 4; ++a)
#pragma unroll
    for (int b = 0; b < 4; ++b) { f32x4 z = {0.f, 0.f, 0.f, 0.f}; acc[a][b] = z; }

  const int NT = DDIM / 64;  // 8 (even)
  STAGE_TILE(0, As0, Bs0);
  __syncthreads();
  for (int t = 0; t < NT; t += 2) {
    if (t + 1 < NT) STAGE_TILE((t + 1) * 64, As1, Bs1);
    COMPUTE_TILE(As0, Bs0);
    __syncthreads();  // drains prefetch vmcnt AFTER compute; syncs buffer reuse
    if (t + 2 < NT) STAGE_TILE((t + 2) * 64, As0, Bs0);
    COMPUTE_TILE(As1, Bs1);
    __syncthreads();
  }

#pragma unroll
  for (int mf = 0; mf < 4; ++mf) {
#pragma unroll
    for (int r = 0; r < 4; ++r) {
      const int row = wm * 64 + mf * 16 + g * 4 + r;
      const int slot = slot0 + row;
      if (slot >= shi) continue;
#pragma unroll
      for (int nf = 0; nf < 4; ++nf) {
        const int col = wn * 64 + nf * 16 + l15;
        float v = acc[mf][nf][r] + b1[e * HID + c0 + n0 + col];
        v = 0.5f * v * (1.0f + erff(v * 0.70710678118654752f));  // exact gelu
        h[(size_t)slot * hc + n0 + col] = (f16)v;
      }
    }
  }
}

// ---------------- GEMM2: out += wgt * (h @ w2[e] + b2[e]) ----------------
__global__ __launch_bounds__(256) void k_mlp2(
    const f16* __restrict__ h, const f16* __restrict__ w2t,
    const float* __restrict__ b2, float* __restrict__ out,
    const int* __restrict__ tok_slot, const float* __restrict__ wgt_slot,
    const int* __restrict__ base, const int* __restrict__ cnt,
    const int hc, const int c0) {
  const int e = blockIdx.z;
  const int ne = cnt[e];
  const int m0 = blockIdx.x * 128;
  if (m0 >= ne) return;
  const int n0 = blockIdx.y * 128;
  const int sbase = base[e];
  const int slot0 = sbase + m0;
  const int shi = sbase + ne;

  __shared__ f16 As0[128 * 64];
  __shared__ f16 Bs0[128 * 64];
  __shared__ f16 As1[128 * 64];
  __shared__ f16 Bs1[128 * 64];

  const int tid = threadIdx.x;
  const int lane = tid & 63;
  const int wv = tid >> 6;
  const int wm = wv >> 1, wn = wv & 1;
  const int g = lane >> 4;
  const int l15 = lane & 15;

  const f16* aSrc[4];
  const f16* bSrc[4];
#pragma unroll
  for (int i = 0; i < 4; ++i) {
    const int ch = wv * 4 + i;
    const int row = ch * 8 + (lane >> 3);
    const int p = lane & 7;
    const int sw = (p ^ (row & 7)) * 8;
    int slot = slot0 + row;
    slot = (slot <= 2 * T_TOK - 1) ? slot : (2 * T_TOK - 1);  // stay in h buffer
    aSrc[i] = h + (size_t)slot * hc + sw;
    bSrc[i] = w2t + (size_t)(e * DDIM + n0 + row) * HID + c0 + sw;
  }

  f32x4 acc[4][4];
#pragma unroll
  for (int a = 0; a < 4; ++a)
#pragma unroll
    for (int b = 0; b < 4; ++b) { f32x4 z = {0.f, 0.f, 0.f, 0.f}; acc[a][b] = z; }

  const int NT = hc / 64;  // 16 for ns=1 (even for all ns)
  STAGE_TILE(0, As0, Bs0);
  __syncthreads();
  for (int t = 0; t < NT; t += 2) {
    if (t + 1 < NT) STAGE_TILE((t + 1) * 64, As1, Bs1);
    COMPUTE_TILE(As0, Bs0);
    __syncthreads();
    if (t + 2 < NT) STAGE_TILE((t + 2) * 64, As0, Bs0);
    COMPUTE_TILE(As1, Bs1);
    __syncthreads();
  }

#pragma unroll
  for (int mf = 0; mf < 4; ++mf) {
#pragma unroll
    for (int r = 0; r < 4; ++r) {
      const int row = wm * 64 + mf * 16 + g * 4 + r;
      const int slot = slot0 + row;
      if (slot >= shi) continue;
      const int tok = tok_slot[slot];
      const float w = wgt_slot[slot];
      float* orow = out + (size_t)tok * DDIM + n0;
#pragma unroll
      for (int nf = 0; nf < 4; ++nf) {
        const int col = wn * 64 + nf * 16 + l15;
        float v = acc[mf][nf][r];
        if (c0 == 0) v += b2[e * DDIM + n0 + col];
        unsafeAtomicAdd(orow + col, w * v);
      }
    }
  }
}

extern "C" void kernel_launch(void* const* d_in, const int* in_sizes, int n_in,
                              void* d_out, int out_size, void* d_ws, size_t ws_size,
                              hipStream_t stream) {
  (void)in_sizes; (void)n_in;
  const float* x  = (const float*)d_in[0];
  const float* gw = (const float*)d_in[1];
  const float* w1 = (const float*)d_in[2];
  const float* b1 = (const float*)d_in[3];
  const float* w2 = (const float*)d_in[4];
  const float* b2 = (const float*)d_in[5];
  float* out = (float*)d_out;

  char* ws = (char*)d_ws;
  size_t off = 0;
  auto alloc = [&](size_t bytes) {
    char* p = ws + off;
    off += (bytes + 255) & ~(size_t)255;
    return p;
  };
  f16*   xh       = (f16*)  alloc((size_t)T_TOK * DDIM * 2);
  f16*   w1t      = (f16*)  alloc((size_t)NEXP * DDIM * HID * 2);
  f16*   w2t      = (f16*)  alloc((size_t)NEXP * DDIM * HID * 2);
  int*   route_e  = (int*)  alloc((size_t)T_TOK * 4);
  float* route_w  = (float*)alloc((size_t)T_TOK * 4);
  int*   tok_slot = (int*)  alloc((size_t)2 * T_TOK * 4);
  float* wgt_slot = (float*)alloc((size_t)2 * T_TOK * 4);
  int*   cnt      = (int*)  alloc(256);
  int*   base     = cnt + 8;
  int*   cursor   = cnt + 16;
  f16*   hbuf     = (f16*)(ws + off);
  const size_t havail = (ws_size > off) ? (ws_size - off) : 0;

  // smallest hidden-split whose h buffer fits the workspace
  int ns = 8;
  const int cands[4] = {1, 2, 4, 8};
  for (int i = 0; i < 4; ++i) {
    if ((size_t)2 * T_TOK * (HID / cands[i]) * 2 <= havail) { ns = cands[i]; break; }
  }
  const int hc = HID / ns;

  hipMemsetAsync(cnt, 0, 32, stream);
  hipMemsetAsync(d_out, 0, (size_t)out_size * sizeof(float), stream);

  k_cvt_x<<<dim3(T_TOK * DDIM / 4 / 256), 256, 0, stream>>>(x, xh);
  k_transpose<<<dim3(DDIM / 64, HID / 64, NEXP), 256, 0, stream>>>(w1, w1t, DDIM, HID);
  k_transpose<<<dim3(HID / 64, DDIM / 64, NEXP), 256, 0, stream>>>(w2, w2t, HID, DDIM);
  k_gate<<<dim3(T_TOK / 32), 256, 0, stream>>>(x, gw, route_e, route_w, cnt);
  k_scan<<<1, 64, 0, stream>>>(cnt, base, cursor, out + (size_t)T_TOK * DDIM);
  k_scatter<<<dim3(T_TOK / 256), 256, 0, stream>>>(route_e, route_w, cursor, tok_slot, wgt_slot);

  for (int c = 0; c < ns; ++c) {
    k_mlp1<<<dim3(256, hc / 128, NEXP), 256, 0, stream>>>(
        xh, w1t, b1, hbuf, tok_slot, base, cnt, hc, c * hc);
    k_mlp2<<<dim3(256, DDIM / 128, NEXP), 256, 0, stream>>>(
        hbuf, w2t, b2, out, tok_slot, wgt_slot, base, cnt, hc, c * hc);
  }
}